// Round 17
// baseline (207.275 us; speedup 1.0000x reference)
//
#include <hip/hip_runtime.h>
#include <stdint.h>
#include <stddef.h>

typedef unsigned short u16;
typedef unsigned int   u32;
typedef unsigned short u16x8 __attribute__((ext_vector_type(8)));
typedef unsigned int   u32x2 __attribute__((ext_vector_type(2)));
typedef __attribute__((ext_vector_type(8))) __bf16 bf16x8;
typedef __attribute__((ext_vector_type(4))) float f32x4;

__device__ __forceinline__ float bf2f(u16 v){
  union { unsigned u; float f; } x; x.u = ((unsigned)v) << 16; return x.f;
}
__device__ __forceinline__ u16 f2bf(float f){
  union { float f; unsigned u; } x; x.f = f;
  return (u16)((x.u + 0x7fffu + ((x.u >> 16) & 1u)) >> 16);
}

__device__ __forceinline__ float exp2_fast(float x){
  float r; asm("v_exp_f32 %0, %1" : "=v"(r) : "v"(x)); return r;
}
__device__ __forceinline__ u32 cvt_pk_bf16(float lo, float hi){
  u32 r; asm("v_cvt_pk_bf16_f32 %0, %1, %2" : "=v"(r) : "v"(lo), "v"(hi)); return r;
}

__device__ __forceinline__ f32x4 mfma16(bf16x8 a, bf16x8 b, f32x4 c){
  return __builtin_amdgcn_mfma_f32_16x16x32_bf16(a, b, c, 0, 0, 0);
}

#define AS1 __attribute__((address_space(1)))
#define AS3 __attribute__((address_space(3)))
__device__ __forceinline__ void gload_lds16(const void* g, void* l){
  __builtin_amdgcn_global_load_lds((const AS1 void*)g, (AS3 void*)l, 16, 0, 0);
}

// ---------------- fp32 -> bf16, PRE-SWIZZLED chunks for BK=64 GEMM tiles ----
__global__ void f32_to_bf16_swz(const float* __restrict__ in, u16* __restrict__ out,
                                int total_chunks){
  for (int i = blockIdx.x * blockDim.x + threadIdx.x; i < total_chunks;
       i += gridDim.x * blockDim.x){
    int row = i >> 7, c = i & 127;
    int cs = (c & ~7) | ((c & 7) ^ (row & 7));
    const float* p = in + ((size_t)i << 3);
    float4 v0 = *(const float4*)p;
    float4 v1 = *(const float4*)(p + 4);
    u16x8 o = { f2bf(v0.x), f2bf(v0.y), f2bf(v0.z), f2bf(v0.w),
                f2bf(v1.x), f2bf(v1.y), f2bf(v1.z), f2bf(v1.w) };
    *(u16x8*)(out + (((size_t)row << 7) + cs) * 8) = o;
  }
}

// ---------------- transpose+convert fp32 (R x C) -> bf16 (C x R), swizzled --
__global__ void conv_transpose_swz(const float* __restrict__ in, u16* __restrict__ out,
                                   int R, int C){
  __shared__ float t[32][33];
  int c0 = blockIdx.x * 32, r0 = blockIdx.y * 32;
  int tx = threadIdx.x, ty = threadIdx.y;
  t[ty][tx] = in[(size_t)(r0 + ty) * C + c0 + tx];
  __syncthreads();
  int tid = ty * 32 + tx;
  if (tid < 128){
    int orow = tid >> 2, oc = tid & 3;
    int gr = c0 + orow;
    int gc = (r0 >> 3) + oc;
    int gcs = (gc & ~7) | ((gc & 7) ^ (gr & 7));
    u16x8 v;
#pragma unroll
    for (int i = 0; i < 8; i++) v[i] = f2bf(t[oc * 8 + i][orow]);
    *(u16x8*)(out + (size_t)gr * R + gcs * 8) = v;
  }
}

// ---------------- pack cos/sin into float2 table ----------------------------
__global__ void pack_cs(const float* __restrict__ cosb, const float* __restrict__ sinb,
                        float2* __restrict__ cs, int n){
  int i = blockIdx.x * 256 + threadIdx.x;
  if (i < n) cs[i] = (float2){cosb[i], sinb[i]};
}

// ---------------- GEMM: BMx256 tile, BK=64, 8 waves, 3-buf A, direct-L2 B ---
// EPI: 1 = fused QKV epilogue (RMSNorm+RoPE+relayout), 2 = f32 C.
template<int BM, int WM, int EPI>
__global__ __launch_bounds__(512, 2)
void gemm256(const u16* __restrict__ A, const u16* __restrict__ Bt,
             void* __restrict__ Cv, int M, int N, int K,
             const float2* __restrict__ cs, const float* __restrict__ qw,
             const float* __restrict__ kw, u16* __restrict__ Qn,
             u16* __restrict__ Kn, u16* __restrict__ Vn){
  constexpr int MF = WM / 16;
  constexpr int ALOADS = BM / 64;
  __shared__ __align__(16) u16 Ab[3][BM * 64];
  const int tid = threadIdx.x;
  const int wid = tid >> 6, lane = tid & 63;
  const int g = lane >> 4, col = lane & 15;
  const int wm = wid >> 2, wn = wid & 3;
  const int swz = col & 7;

  int nb  = gridDim.x * gridDim.y;
  int lid = blockIdx.y * gridDim.x + blockIdx.x;
  int cpx = nb >> 3;
  int sid = (lid & 7) * cpx + (lid >> 3);
  int bx  = sid % gridDim.x, by = sid / gridDim.x;
  const int m0 = by * BM, n0 = bx * 256;

  f32x4 acc[MF][4];
#pragma unroll
  for (int i = 0; i < MF; i++)
#pragma unroll
    for (int j = 0; j < 4; j++) acc[i][j] = (f32x4){0.f, 0.f, 0.f, 0.f};

  const int arow = wid * 8 + (lane >> 3);
  const int acl  = (lane & 7) * 8;

  auto STAGE_A = [&](int bi, int k0){
#pragma unroll
    for (int j = 0; j < ALOADS; j++)
      gload_lds16(A + (size_t)(m0 + j * 64 + arow) * K + k0 + acl,
                  &Ab[bi][j * 4096 + wid * 512]);
  };

  const int NT = K >> 6;
  STAGE_A(0, 0);
  STAGE_A(1, 64);
  if (ALOADS == 4) asm volatile("s_waitcnt vmcnt(4)");
  else             asm volatile("s_waitcnt vmcnt(2)");
  __builtin_amdgcn_sched_barrier(0);
  __builtin_amdgcn_s_barrier();
  __builtin_amdgcn_sched_barrier(0);

  int cb = 0, sa = 2;
  for (int t = 0; t < NT; ++t){
    bf16x8 bfr[4][2];
#pragma unroll
    for (int ni = 0; ni < 4; ni++){
      const u16* bp = Bt + (size_t)(n0 + wn * 64 + ni * 16 + col) * K + t * 64;
#pragma unroll
      for (int ks = 0; ks < 2; ks++)
        bfr[ni][ks] = *(const bf16x8*)(bp + (((ks * 4 + g) ^ swz) << 3));
    }
    __builtin_amdgcn_sched_barrier(0);
    if (t + 2 < NT) STAGE_A(sa, (t + 2) * 64);
    __builtin_amdgcn_sched_barrier(0);

    const u16* Ac = &Ab[cb][0];
#pragma unroll
    for (int ph = 0; ph < MF / 4; ++ph){
      bf16x8 afr[4][2];
#pragma unroll
      for (int m2 = 0; m2 < 4; m2++){
        int row = wm * WM + (ph * 4 + m2) * 16 + col;
#pragma unroll
        for (int ks = 0; ks < 2; ks++)
          afr[m2][ks] = *(const bf16x8*)&Ac[row * 64 + (((ks * 4 + g) ^ swz) << 3)];
      }
      __builtin_amdgcn_s_setprio(1);
#pragma unroll
      for (int m2 = 0; m2 < 4; m2++)
#pragma unroll
        for (int ni = 0; ni < 4; ni++)
#pragma unroll
          for (int ks = 0; ks < 2; ks++)
            acc[ph * 4 + m2][ni] =
                mfma16(afr[m2][ks], bfr[ni][ks], acc[ph * 4 + m2][ni]);
      __builtin_amdgcn_s_setprio(0);
    }

    asm volatile("s_waitcnt lgkmcnt(0)");
    __builtin_amdgcn_sched_barrier(0);
    if (t + 2 < NT){
      if (ALOADS == 4) asm volatile("s_waitcnt vmcnt(4)");
      else             asm volatile("s_waitcnt vmcnt(2)");
    } else {
      asm volatile("s_waitcnt vmcnt(0)");
    }
    __builtin_amdgcn_sched_barrier(0);
    __builtin_amdgcn_s_barrier();
    __builtin_amdgcn_sched_barrier(0);
    cb = (cb == 2) ? 0 : cb + 1;
    sa = (sa == 2) ? 0 : sa + 1;
  }

  if (EPI == 1){
    // ---- fused RMSNorm + RoPE + relayout epilogue ----
    const int colbase = n0 + wn * 64;    // wave owns one 64-wide head
    const int t0 = m0 + wm * WM;
    const int bb = t0 >> 11;
    if (colbase < 1536){
      const bool isQ = colbase < 1024;
      const int head = isQ ? (colbase >> 6) : ((colbase - 1024) >> 6);
      const float* wp = isQ ? qw : kw;
      float wv[4];
#pragma unroll
      for (int ni = 0; ni < 4; ni++) wv[ni] = wp[ni * 16 + col];
      u16* outp = isQ ? Qn : Kn;
      size_t hb = isQ ? ((size_t)(bb * 16 + head) * 2048)
                      : ((size_t)(bb * 8 + head) * 2048);
#pragma unroll
      for (int mi = 0; mi < MF; mi++){
        f32x4 ssv = (f32x4){0.f, 0.f, 0.f, 0.f};
#pragma unroll
        for (int ni = 0; ni < 4; ni++)
#pragma unroll
          for (int r = 0; r < 4; r++) ssv[r] += acc[mi][ni][r] * acc[mi][ni][r];
#pragma unroll
        for (int off = 1; off < 16; off <<= 1)
#pragma unroll
          for (int r = 0; r < 4; r++) ssv[r] += __shfl_xor(ssv[r], off, 64);
        f32x4 rinv;
#pragma unroll
        for (int r = 0; r < 4; r++) rinv[r] = rsqrtf(ssv[r] * (1.f / 64.f) + 1e-6f);
        int s0 = (t0 + mi * 16 + g * 4) & 2047;
#pragma unroll
        for (int np = 0; np < 2; np++){
          int d0 = np * 32 + col, d1 = d0 + 16;
#pragma unroll
          for (int r = 0; r < 4; r++){
            int s = s0 + r;
            float y0 = acc[mi][np * 2][r]     * rinv[r] * wv[np * 2];
            float y1 = acc[mi][np * 2 + 1][r] * rinv[r] * wv[np * 2 + 1];
            float2 c0 = cs[s * 64 + d0];
            float2 c1 = cs[s * 64 + d1];
            float o0 = y0 * c0.x - y1 * c0.y;
            float o1 = y1 * c1.x + y0 * c1.y;
            if (isQ){
              outp[(hb + s) * 64 + d0] = f2bf(o0);
              outp[(hb + s) * 64 + d1] = f2bf(o1);
            } else {
              int z0 = ((((d0 >> 3) ^ s) & 7) << 3) | (d0 & 7);
              int z1 = ((((d1 >> 3) ^ s) & 7) << 3) | (d1 & 7);
              outp[(hb + s) * 64 + z0] = f2bf(o0);
              outp[(hb + s) * 64 + z1] = f2bf(o1);
            }
          }
        }
      }
    } else {
      const int kvh = (colbase - 1536) >> 6;
      const size_t vb0 = (size_t)(bb * 8 + kvh) * 64;
#pragma unroll
      for (int mi = 0; mi < MF; mi++){
        f32x4 ssv = (f32x4){0.f, 0.f, 0.f, 0.f};
#pragma unroll
        for (int ni = 0; ni < 4; ni++)
#pragma unroll
          for (int r = 0; r < 4; r++) ssv[r] += acc[mi][ni][r] * acc[mi][ni][r];
#pragma unroll
        for (int off = 1; off < 16; off <<= 1)
#pragma unroll
          for (int r = 0; r < 4; r++) ssv[r] += __shfl_xor(ssv[r], off, 64);
        f32x4 rinv;
#pragma unroll
        for (int r = 0; r < 4; r++) rinv[r] = rsqrtf(ssv[r] * (1.f / 64.f) + 1e-6f);
        int s0 = (t0 + mi * 16 + g * 4) & 2047;
#pragma unroll
        for (int ni = 0; ni < 4; ni++){
          int d = ni * 16 + col;
          uint2 o;
          o.x = cvt_pk_bf16(acc[mi][ni][0] * rinv[0], acc[mi][ni][1] * rinv[1]);
          o.y = cvt_pk_bf16(acc[mi][ni][2] * rinv[2], acc[mi][ni][3] * rinv[3]);
          size_t addr = (vb0 + d) * 2048 + (s0 & ~63)
                      + ((((s0 >> 3) ^ (d & 7)) & 7) << 3) + (s0 & 7);
          *(uint2*)(Vn + addr) = o;
        }
      }
    }
    return;
  }

#pragma unroll
  for (int mi = 0; mi < MF; mi++)
#pragma unroll
    for (int ni = 0; ni < 4; ni++)
#pragma unroll
      for (int r = 0; r < 4; r++){
        int row = m0 + wm * WM + mi * 16 + g * 4 + r;
        int cc  = n0 + wn * 64 + ni * 16 + col;
        ((float*)Cv)[(size_t)row * N + cc] = acc[mi][ni][r];
      }
}

// ---------------- Flash attention: 8 waves (4 q x 2 kg), in-register P,
// 2-buffer K/V, l summed on VALU (lane-local, 2 shuffles at end only) --------
__global__ __launch_bounds__(512, 2)
void flash_attn(const u16* __restrict__ Qn, const u16* __restrict__ Kn,
                const u16* __restrict__ Vn, u16* __restrict__ AO){
  const int S = 2048;
  const float L2E = 1.4426950408889634f;
  const float C2 = 30.f;
  const int b = blockIdx.z, h = blockIdx.y, qt = blockIdx.x;
  const int kvh = h >> 1;
  const int wid = threadIdx.x >> 6, lane = threadIdx.x & 63;
  const int kg = wid >> 2, wq = wid & 3;
  const int g = lane >> 4, col = lane & 15;
  const int q0 = qt * 256 + wq * 64;

  // 68KB LDS: K [2kg][2buf][4096] u16 = 32KB, V same = 32KB; combine +4KB.
  __shared__ __align__(16) u16 lds[34816];
  u16* Kl = lds + kg * 8192;
  u16* Vl = lds + 16384 + kg * 8192;

  bf16x8 aq[4][2];
#pragma unroll
  for (int cg = 0; cg < 4; cg++){
    const u16* qp = Qn + ((size_t)((b * 16 + h) * S) + q0 + cg * 16 + col) * 64;
    aq[cg][0] = *(const bf16x8*)(qp + g * 8);
    aq[cg][1] = *(const bf16x8*)(qp + 32 + g * 8);
  }

  const u16* Kbase = Kn + (size_t)(b * 8 + kvh) * S * 64 + (size_t)kg * 1024 * 64;
  const u16* Vbase = Vn + (size_t)(b * 8 + kvh) * 64 * S;
  const int vcol0 = kg * 1024;

  f32x4 acc[4][4];
  float lsum[4] = {0.f, 0.f, 0.f, 0.f};
#pragma unroll
  for (int cg = 0; cg < 4; cg++)
#pragma unroll
    for (int i = 0; i < 4; i++) acc[cg][i] = (f32x4){0.f, 0.f, 0.f, 0.f};

  const int sw = col & 7;

  auto STAGE = [&](int bi, int ktl){
    int kc0 = ktl * 64;
#pragma unroll
    for (int cc = 0; cc < 2; cc++){
      int chunk = cc * 4 + wq;
      gload_lds16(Kbase + (size_t)kc0 * 64 + chunk * 512 + lane * 8,
                  Kl + bi * 4096 + chunk * 512);
      int drow = chunk * 8 + (lane >> 3);
      gload_lds16(Vbase + (size_t)drow * S + vcol0 + kc0 + (lane & 7) * 8,
                  Vl + bi * 4096 + chunk * 512);
    }
  };

  int buf = 0;
  STAGE(0, 0);
  __syncthreads();

  for (int kt = 0; kt < 16; ++kt){
    if (kt + 1 < 16) STAGE(buf ^ 1, kt + 1);

    const u16* Kb = Kl + buf * 4096;
    const u16* Vb = Vl + buf * 4096;

    bf16x8 kf[4][2], vf[4][2];
#pragma unroll
    for (int c = 0; c < 4; c++){
      const u16* kb = Kb + (c * 16 + col) * 64;
      kf[c][0] = *(const bf16x8*)(kb + (g ^ sw) * 8);
      kf[c][1] = *(const bf16x8*)(kb + ((4 + g) ^ sw) * 8);
      const u16* vb = Vb + (c * 16 + col) * 64;
      vf[c][0] = *(const bf16x8*)(vb + (g ^ sw) * 8);
      vf[c][1] = *(const bf16x8*)(vb + ((4 + g) ^ sw) * 8);
    }

#pragma unroll
    for (int cg = 0; cg < 4; cg++){
      f32x4 sf[4];
      __builtin_amdgcn_s_setprio(1);
#pragma unroll
      for (int c = 0; c < 4; c++){
        f32x4 z = (f32x4){0.f, 0.f, 0.f, 0.f};
        z = mfma16(kf[c][0], aq[cg][0], z);
        sf[c] = mfma16(kf[c][1], aq[cg][1], z);
      }
      __builtin_amdgcn_s_setprio(0);

      // exp + lane-local l accumulation + pack
      uint2 pw[4];
#pragma unroll
      for (int c = 0; c < 4; c++){
        float p0 = exp2_fast(__builtin_fmaf(sf[c][0], L2E, -C2));
        float p1 = exp2_fast(__builtin_fmaf(sf[c][1], L2E, -C2));
        float p2 = exp2_fast(__builtin_fmaf(sf[c][2], L2E, -C2));
        float p3 = exp2_fast(__builtin_fmaf(sf[c][3], L2E, -C2));
        lsum[cg] += (p0 + p1) + (p2 + p3);
        pw[c].x = cvt_pk_bf16(p0, p1);
        pw[c].y = cvt_pk_bf16(p2, p3);
      }

      // build K=32 B-fragments via permlane swaps (2 spans: c{0,1}, c{2,3})
      bf16x8 pf[2];
#pragma unroll
      for (int sp = 0; sp < 2; sp++){
        u32x2 tx = __builtin_amdgcn_permlane32_swap(pw[sp*2].x, pw[sp*2+1].x, false, false);
        u32x2 fx = __builtin_amdgcn_permlane16_swap(tx.x, tx.y, false, false);
        u32x2 ty = __builtin_amdgcn_permlane32_swap(pw[sp*2].y, pw[sp*2+1].y, false, false);
        u32x2 fy = __builtin_amdgcn_permlane16_swap(ty.x, ty.y, false, false);
        union { u32 w[4]; bf16x8 v; } pu;
        pu.w[0] = fx.x;   // rows g*8+0,1
        pu.w[1] = fy.x;   // rows g*8+2,3
        pu.w[2] = fx.y;   // rows g*8+4,5
        pu.w[3] = fy.y;   // rows g*8+6,7
        pf[sp] = pu.v;
      }

      __builtin_amdgcn_s_setprio(1);
#pragma unroll
      for (int cd = 0; cd < 4; cd++){
        acc[cg][cd] = mfma16(vf[cd][0], pf[0], acc[cg][cd]);
        acc[cg][cd] = mfma16(vf[cd][1], pf[1], acc[cg][cd]);
      }
      __builtin_amdgcn_s_setprio(0);
    }

    __syncthreads();
    buf ^= 1;
  }

  // reduce l across the 4 g-groups (once, not per tile)
#pragma unroll
  for (int cg = 0; cg < 4; cg++){
    lsum[cg] += __shfl_xor(lsum[cg], 16, 64);
    lsum[cg] += __shfl_xor(lsum[cg], 32, 64);
  }

  // ---- combine the two k-halves (scratch aliases dead K/V LDS) -------------
  f32x4* sAcc = (f32x4*)lds;                     // 16*256 f32x4 = 64KB
  float*  sL  = (float*)((char*)lds + 65536);    // 4*256 f32 = 4KB
  if (kg == 1){
#pragma unroll
    for (int cg = 0; cg < 4; cg++){
#pragma unroll
      for (int cd = 0; cd < 4; cd++)
        sAcc[(cg * 4 + cd) * 256 + wq * 64 + lane] = acc[cg][cd];
      sL[cg * 256 + wq * 64 + lane] = lsum[cg];
    }
  }
  __syncthreads();
  if (kg == 0){
#pragma unroll
    for (int cg = 0; cg < 4; cg++){
      float l = lsum[cg] + sL[cg * 256 + wq * 64 + lane];
      float linv = 1.f / l;
      int s = q0 + cg * 16 + col;
#pragma unroll
      for (int cd = 0; cd < 4; cd++){
        f32x4 a = acc[cg][cd] + sAcc[(cg * 4 + cd) * 256 + wq * 64 + lane];
        uint2 o;
        o.x = cvt_pk_bf16(a[0] * linv, a[1] * linv);
        o.y = cvt_pk_bf16(a[2] * linv, a[3] * linv);
        int pc = (cd * 2 + (g >> 1)) ^ sw;   // pre-swizzle for Wo GEMM
        *(uint2*)(AO + (size_t)(b * S + s) * 1024 + h * 64 + pc * 8 + (g & 1) * 4) = o;
      }
    }
  }
}

// ---------------- host-side launch ------------------------------------------
extern "C" void kernel_launch(void* const* d_in, const int* in_sizes, int n_in,
                              void* d_out, int out_size, void* d_ws, size_t ws_size,
                              hipStream_t stream){
  const int Btok = 8192;          // B*S
  const float* hs   = (const float*)d_in[0];
  const float* cosb = (const float*)d_in[1];
  const float* sinb = (const float*)d_in[2];
  const float* Wq = (const float*)d_in[5];
  const float* Wk = (const float*)d_in[6];
  const float* Wv = (const float*)d_in[7];
  const float* Wo = (const float*)d_in[8];
  const float* qw = (const float*)d_in[9];
  const float* kw = (const float*)d_in[10];
  float* out = (float*)d_out;

  char* ws = (char*)d_ws;
  u16* hsB   = (u16*)ws;               ws += (size_t)Btok * 1024 * 2;   // 16MB
  u16* WqkvT = (u16*)ws;               ws += (size_t)2048 * 1024 * 2;   // 4MB
  u16* WoT   = (u16*)ws;               ws += (size_t)1024 * 1024 * 2;   // 2MB
  u16* Qn    = (u16*)ws;               ws += (size_t)Btok * 1024 * 2;   // 16MB
  u16* Kn    = (u16*)ws;               ws += (size_t)Btok * 512  * 2;   // 8MB
  u16* Vn    = (u16*)ws;               ws += (size_t)Btok * 512  * 2;   // 8MB
  float2* cst = (float2*)ws;           ws += (size_t)2048 * 64 * 8;     // 1MB
  u16* AO    = hsB;                    // alias: hsB dead after QKV GEMM

  f32_to_bf16_swz<<<2048, 256, 0, stream>>>(hs, hsB, Btok * 128);

  dim3 tb(32, 32);
  conv_transpose_swz<<<dim3(32, 32), tb, 0, stream>>>(Wq, WqkvT,               1024, 1024);
  conv_transpose_swz<<<dim3(16, 32), tb, 0, stream>>>(Wk, WqkvT + 1024 * 1024, 1024, 512);
  conv_transpose_swz<<<dim3(16, 32), tb, 0, stream>>>(Wv, WqkvT + 1536 * 1024, 1024, 512);
  conv_transpose_swz<<<dim3(32, 32), tb, 0, stream>>>(Wo, WoT,                 1024, 1024);
  pack_cs<<<512, 256, 0, stream>>>(cosb, sinb, cst, 2048 * 64);

  // BM=128: 48KB LDS -> 2 blocks/CU, 512 blocks, 16 waves/CU
  gemm256<128, 64, 1><<<dim3(8, 64), 512, 0, stream>>>(
      hsB, WqkvT, nullptr, Btok, 2048, 1024, cst, qw, kw, Qn, Kn, Vn);

  flash_attn<<<dim3(8, 16, 4), 512, 0, stream>>>(Qn, Kn, Vn, AO);

  gemm256<128, 64, 2><<<dim3(4, 64), 512, 0, stream>>>(
      AO, WoT, out, Btok, 1024, 1024, nullptr, nullptr, nullptr,
      nullptr, nullptr, nullptr);
}

// Round 18
// 184.199 us; speedup vs baseline: 1.1253x; 1.1253x over previous
//
#include <hip/hip_runtime.h>
#include <stdint.h>
#include <stddef.h>

typedef unsigned short u16;
typedef unsigned int   u32;
typedef unsigned short u16x8 __attribute__((ext_vector_type(8)));
typedef unsigned int   u32x2 __attribute__((ext_vector_type(2)));
typedef __attribute__((ext_vector_type(8))) __bf16 bf16x8;
typedef __attribute__((ext_vector_type(4))) float f32x4;

__device__ __forceinline__ float bf2f(u16 v){
  union { unsigned u; float f; } x; x.u = ((unsigned)v) << 16; return x.f;
}
__device__ __forceinline__ u16 f2bf(float f){
  union { float f; unsigned u; } x; x.f = f;
  return (u16)((x.u + 0x7fffu + ((x.u >> 16) & 1u)) >> 16);
}

__device__ __forceinline__ float exp2_fast(float x){
  float r; asm("v_exp_f32 %0, %1" : "=v"(r) : "v"(x)); return r;
}
__device__ __forceinline__ u32 cvt_pk_bf16(float lo, float hi){
  u32 r; asm("v_cvt_pk_bf16_f32 %0, %1, %2" : "=v"(r) : "v"(lo), "v"(hi)); return r;
}

__device__ __forceinline__ f32x4 mfma16(bf16x8 a, bf16x8 b, f32x4 c){
  return __builtin_amdgcn_mfma_f32_16x16x32_bf16(a, b, c, 0, 0, 0);
}

#define AS1 __attribute__((address_space(1)))
#define AS3 __attribute__((address_space(3)))
__device__ __forceinline__ void gload_lds16(const void* g, void* l){
  __builtin_amdgcn_global_load_lds((const AS1 void*)g, (AS3 void*)l, 16, 0, 0);
}

// ---------------- fp32 -> bf16, PRE-SWIZZLED chunks for BK=64 GEMM tiles ----
__global__ void f32_to_bf16_swz(const float* __restrict__ in, u16* __restrict__ out,
                                int total_chunks){
  for (int i = blockIdx.x * blockDim.x + threadIdx.x; i < total_chunks;
       i += gridDim.x * blockDim.x){
    int row = i >> 7, c = i & 127;
    int cs = (c & ~7) | ((c & 7) ^ (row & 7));
    const float* p = in + ((size_t)i << 3);
    float4 v0 = *(const float4*)p;
    float4 v1 = *(const float4*)(p + 4);
    u16x8 o = { f2bf(v0.x), f2bf(v0.y), f2bf(v0.z), f2bf(v0.w),
                f2bf(v1.x), f2bf(v1.y), f2bf(v1.z), f2bf(v1.w) };
    *(u16x8*)(out + (((size_t)row << 7) + cs) * 8) = o;
  }
}

// ---------------- transpose+convert fp32 (R x C) -> bf16 (C x R), swizzled --
__global__ void conv_transpose_swz(const float* __restrict__ in, u16* __restrict__ out,
                                   int R, int C){
  __shared__ float t[32][33];
  int c0 = blockIdx.x * 32, r0 = blockIdx.y * 32;
  int tx = threadIdx.x, ty = threadIdx.y;
  t[ty][tx] = in[(size_t)(r0 + ty) * C + c0 + tx];
  __syncthreads();
  int tid = ty * 32 + tx;
  if (tid < 128){
    int orow = tid >> 2, oc = tid & 3;
    int gr = c0 + orow;
    int gc = (r0 >> 3) + oc;
    int gcs = (gc & ~7) | ((gc & 7) ^ (gr & 7));
    u16x8 v;
#pragma unroll
    for (int i = 0; i < 8; i++) v[i] = f2bf(t[oc * 8 + i][orow]);
    *(u16x8*)(out + (size_t)gr * R + gcs * 8) = v;
  }
}

// ---------------- pack cos/sin into float2 table ----------------------------
__global__ void pack_cs(const float* __restrict__ cosb, const float* __restrict__ sinb,
                        float2* __restrict__ cs, int n){
  int i = blockIdx.x * 256 + threadIdx.x;
  if (i < n) cs[i] = (float2){cosb[i], sinb[i]};
}

// ---------------- GEMM: BMx256 tile, BK=64, 8 waves, 3-buf A, direct-L2 B ---
// EPI: 1 = fused QKV epilogue (RMSNorm+RoPE+relayout), 2 = f32 C.
template<int BM, int WM, int EPI>
__global__ __launch_bounds__(512, 2)
void gemm256(const u16* __restrict__ A, const u16* __restrict__ Bt,
             void* __restrict__ Cv, int M, int N, int K,
             const float2* __restrict__ cs, const float* __restrict__ qw,
             const float* __restrict__ kw, u16* __restrict__ Qn,
             u16* __restrict__ Kn, u16* __restrict__ Vn){
  constexpr int MF = WM / 16;
  constexpr int ALOADS = BM / 64;
  __shared__ __align__(16) u16 Ab[3][BM * 64];
  const int tid = threadIdx.x;
  const int wid = tid >> 6, lane = tid & 63;
  const int g = lane >> 4, col = lane & 15;
  const int wm = wid >> 2, wn = wid & 3;
  const int swz = col & 7;

  int nb  = gridDim.x * gridDim.y;
  int lid = blockIdx.y * gridDim.x + blockIdx.x;
  int cpx = nb >> 3;
  int sid = (lid & 7) * cpx + (lid >> 3);
  int bx  = sid % gridDim.x, by = sid / gridDim.x;
  const int m0 = by * BM, n0 = bx * 256;

  f32x4 acc[MF][4];
#pragma unroll
  for (int i = 0; i < MF; i++)
#pragma unroll
    for (int j = 0; j < 4; j++) acc[i][j] = (f32x4){0.f, 0.f, 0.f, 0.f};

  const int arow = wid * 8 + (lane >> 3);
  const int acl  = (lane & 7) * 8;

  auto STAGE_A = [&](int bi, int k0){
#pragma unroll
    for (int j = 0; j < ALOADS; j++)
      gload_lds16(A + (size_t)(m0 + j * 64 + arow) * K + k0 + acl,
                  &Ab[bi][j * 4096 + wid * 512]);
  };

  const int NT = K >> 6;
  STAGE_A(0, 0);
  STAGE_A(1, 64);
  if (ALOADS == 4) asm volatile("s_waitcnt vmcnt(4)");
  else             asm volatile("s_waitcnt vmcnt(2)");
  __builtin_amdgcn_sched_barrier(0);
  __builtin_amdgcn_s_barrier();
  __builtin_amdgcn_sched_barrier(0);

  int cb = 0, sa = 2;
  for (int t = 0; t < NT; ++t){
    bf16x8 bfr[4][2];
#pragma unroll
    for (int ni = 0; ni < 4; ni++){
      const u16* bp = Bt + (size_t)(n0 + wn * 64 + ni * 16 + col) * K + t * 64;
#pragma unroll
      for (int ks = 0; ks < 2; ks++)
        bfr[ni][ks] = *(const bf16x8*)(bp + (((ks * 4 + g) ^ swz) << 3));
    }
    __builtin_amdgcn_sched_barrier(0);
    if (t + 2 < NT) STAGE_A(sa, (t + 2) * 64);
    __builtin_amdgcn_sched_barrier(0);

    const u16* Ac = &Ab[cb][0];
#pragma unroll
    for (int ph = 0; ph < MF / 4; ++ph){
      bf16x8 afr[4][2];
#pragma unroll
      for (int m2 = 0; m2 < 4; m2++){
        int row = wm * WM + (ph * 4 + m2) * 16 + col;
#pragma unroll
        for (int ks = 0; ks < 2; ks++)
          afr[m2][ks] = *(const bf16x8*)&Ac[row * 64 + (((ks * 4 + g) ^ swz) << 3)];
      }
      __builtin_amdgcn_s_setprio(1);
#pragma unroll
      for (int m2 = 0; m2 < 4; m2++)
#pragma unroll
        for (int ni = 0; ni < 4; ni++)
#pragma unroll
          for (int ks = 0; ks < 2; ks++)
            acc[ph * 4 + m2][ni] =
                mfma16(afr[m2][ks], bfr[ni][ks], acc[ph * 4 + m2][ni]);
      __builtin_amdgcn_s_setprio(0);
    }

    asm volatile("s_waitcnt lgkmcnt(0)");
    __builtin_amdgcn_sched_barrier(0);
    if (t + 2 < NT){
      if (ALOADS == 4) asm volatile("s_waitcnt vmcnt(4)");
      else             asm volatile("s_waitcnt vmcnt(2)");
    } else {
      asm volatile("s_waitcnt vmcnt(0)");
    }
    __builtin_amdgcn_sched_barrier(0);
    __builtin_amdgcn_s_barrier();
    __builtin_amdgcn_sched_barrier(0);
    cb = (cb == 2) ? 0 : cb + 1;
    sa = (sa == 2) ? 0 : sa + 1;
  }

  if (EPI == 1){
    // ---- fused RMSNorm + RoPE + relayout epilogue ----
    const int colbase = n0 + wn * 64;    // wave owns one 64-wide head
    const int t0 = m0 + wm * WM;
    const int bb = t0 >> 11;
    if (colbase < 1536){
      const bool isQ = colbase < 1024;
      const int head = isQ ? (colbase >> 6) : ((colbase - 1024) >> 6);
      const float* wp = isQ ? qw : kw;
      float wv[4];
#pragma unroll
      for (int ni = 0; ni < 4; ni++) wv[ni] = wp[ni * 16 + col];
      u16* outp = isQ ? Qn : Kn;
      size_t hb = isQ ? ((size_t)(bb * 16 + head) * 2048)
                      : ((size_t)(bb * 8 + head) * 2048);
#pragma unroll
      for (int mi = 0; mi < MF; mi++){
        f32x4 ssv = (f32x4){0.f, 0.f, 0.f, 0.f};
#pragma unroll
        for (int ni = 0; ni < 4; ni++)
#pragma unroll
          for (int r = 0; r < 4; r++) ssv[r] += acc[mi][ni][r] * acc[mi][ni][r];
#pragma unroll
        for (int off = 1; off < 16; off <<= 1)
#pragma unroll
          for (int r = 0; r < 4; r++) ssv[r] += __shfl_xor(ssv[r], off, 64);
        f32x4 rinv;
#pragma unroll
        for (int r = 0; r < 4; r++) rinv[r] = rsqrtf(ssv[r] * (1.f / 64.f) + 1e-6f);
        int s0 = (t0 + mi * 16 + g * 4) & 2047;
#pragma unroll
        for (int np = 0; np < 2; np++){
          int d0 = np * 32 + col, d1 = d0 + 16;
#pragma unroll
          for (int r = 0; r < 4; r++){
            int s = s0 + r;
            float y0 = acc[mi][np * 2][r]     * rinv[r] * wv[np * 2];
            float y1 = acc[mi][np * 2 + 1][r] * rinv[r] * wv[np * 2 + 1];
            float2 c0 = cs[s * 64 + d0];
            float2 c1 = cs[s * 64 + d1];
            float o0 = y0 * c0.x - y1 * c0.y;
            float o1 = y1 * c1.x + y0 * c1.y;
            if (isQ){
              outp[(hb + s) * 64 + d0] = f2bf(o0);
              outp[(hb + s) * 64 + d1] = f2bf(o1);
            } else {
              int z0 = ((((d0 >> 3) ^ s) & 7) << 3) | (d0 & 7);
              int z1 = ((((d1 >> 3) ^ s) & 7) << 3) | (d1 & 7);
              outp[(hb + s) * 64 + z0] = f2bf(o0);
              outp[(hb + s) * 64 + z1] = f2bf(o1);
            }
          }
        }
      }
    } else {
      const int kvh = (colbase - 1536) >> 6;
      const size_t vb0 = (size_t)(bb * 8 + kvh) * 64;
#pragma unroll
      for (int mi = 0; mi < MF; mi++){
        f32x4 ssv = (f32x4){0.f, 0.f, 0.f, 0.f};
#pragma unroll
        for (int ni = 0; ni < 4; ni++)
#pragma unroll
          for (int r = 0; r < 4; r++) ssv[r] += acc[mi][ni][r] * acc[mi][ni][r];
#pragma unroll
        for (int off = 1; off < 16; off <<= 1)
#pragma unroll
          for (int r = 0; r < 4; r++) ssv[r] += __shfl_xor(ssv[r], off, 64);
        f32x4 rinv;
#pragma unroll
        for (int r = 0; r < 4; r++) rinv[r] = rsqrtf(ssv[r] * (1.f / 64.f) + 1e-6f);
        int s0 = (t0 + mi * 16 + g * 4) & 2047;
#pragma unroll
        for (int ni = 0; ni < 4; ni++){
          int d = ni * 16 + col;
          uint2 o;
          o.x = cvt_pk_bf16(acc[mi][ni][0] * rinv[0], acc[mi][ni][1] * rinv[1]);
          o.y = cvt_pk_bf16(acc[mi][ni][2] * rinv[2], acc[mi][ni][3] * rinv[3]);
          size_t addr = (vb0 + d) * 2048 + (s0 & ~63)
                      + ((((s0 >> 3) ^ (d & 7)) & 7) << 3) + (s0 & 7);
          *(uint2*)(Vn + addr) = o;
        }
      }
    }
    return;
  }

#pragma unroll
  for (int mi = 0; mi < MF; mi++)
#pragma unroll
    for (int ni = 0; ni < 4; ni++)
#pragma unroll
      for (int r = 0; r < 4; r++){
        int row = m0 + wm * WM + mi * 16 + g * 4 + r;
        int cc  = n0 + wn * 64 + ni * 16 + col;
        ((float*)Cv)[(size_t)row * N + cc] = acc[mi][ni][r];
      }
}

// ---------------- Flash attention: 8 waves (4 q x 2 kg), in-register P ------
// r15 configuration (session best) + XCD-grouped 1D grid: all 8 qt-blocks of
// one (h,b) share i%8, so they land on one XCD and share its L2 K/V panel.
__global__ __launch_bounds__(512, 2)
void flash_attn(const u16* __restrict__ Qn, const u16* __restrict__ Kn,
                const u16* __restrict__ Vn, u16* __restrict__ AO){
  const int S = 2048;
  const float L2E = 1.4426950408889634f;
  const float C2 = 30.f;
  // 1D grid 512: i = (hb&7) + 8*qt + 64*(hb>>3), hb = h + 16*b
  const int i = blockIdx.x;
  const int hb = (i & 7) | ((i >> 6) << 3);
  const int qt = (i >> 3) & 7;
  const int h = hb & 15, b = hb >> 4;
  const int kvh = h >> 1;
  const int wid = threadIdx.x >> 6, lane = threadIdx.x & 63;
  const int kg = wid >> 2, wq = wid & 3;
  const int g = lane >> 4, col = lane & 15;
  const int q0 = qt * 256 + wq * 64;

  // 68KB LDS: K [2kg][2buf][4096] u16 = 32KB, V same = 32KB; combine +4KB.
  __shared__ __align__(16) u16 lds[34816];
  u16* Kl = lds + kg * 8192;
  u16* Vl = lds + 16384 + kg * 8192;

  bf16x8 ones;
#pragma unroll
  for (int k = 0; k < 8; k++) ones[k] = (__bf16)1.0f;

  bf16x8 aq[4][2];
#pragma unroll
  for (int cg = 0; cg < 4; cg++){
    const u16* qp = Qn + ((size_t)((b * 16 + h) * S) + q0 + cg * 16 + col) * 64;
    aq[cg][0] = *(const bf16x8*)(qp + g * 8);
    aq[cg][1] = *(const bf16x8*)(qp + 32 + g * 8);
  }

  const u16* Kbase = Kn + (size_t)(b * 8 + kvh) * S * 64 + (size_t)kg * 1024 * 64;
  const u16* Vbase = Vn + (size_t)(b * 8 + kvh) * 64 * S;
  const int vcol0 = kg * 1024;

  f32x4 acc[4][4];
  f32x4 lacc[4];
#pragma unroll
  for (int cg = 0; cg < 4; cg++){
    lacc[cg] = (f32x4){0.f, 0.f, 0.f, 0.f};
#pragma unroll
    for (int k = 0; k < 4; k++) acc[cg][k] = (f32x4){0.f, 0.f, 0.f, 0.f};
  }

  const int sw = col & 7;

  auto STAGE = [&](int bi, int ktl){
    int kc0 = ktl * 64;
#pragma unroll
    for (int cc = 0; cc < 2; cc++){
      int chunk = cc * 4 + wq;
      gload_lds16(Kbase + (size_t)kc0 * 64 + chunk * 512 + lane * 8,
                  Kl + bi * 4096 + chunk * 512);
      int drow = chunk * 8 + (lane >> 3);
      gload_lds16(Vbase + (size_t)drow * S + vcol0 + kc0 + (lane & 7) * 8,
                  Vl + bi * 4096 + chunk * 512);
    }
  };

  int buf = 0;
  STAGE(0, 0);
  __syncthreads();

  for (int kt = 0; kt < 16; ++kt){
    if (kt + 1 < 16) STAGE(buf ^ 1, kt + 1);

    const u16* Kb = Kl + buf * 4096;
    const u16* Vb = Vl + buf * 4096;

    bf16x8 kf[4][2], vf[4][2];
#pragma unroll
    for (int c = 0; c < 4; c++){
      const u16* kb = Kb + (c * 16 + col) * 64;
      kf[c][0] = *(const bf16x8*)(kb + (g ^ sw) * 8);
      kf[c][1] = *(const bf16x8*)(kb + ((4 + g) ^ sw) * 8);
      const u16* vb = Vb + (c * 16 + col) * 64;
      vf[c][0] = *(const bf16x8*)(vb + (g ^ sw) * 8);
      vf[c][1] = *(const bf16x8*)(vb + ((4 + g) ^ sw) * 8);
    }

#pragma unroll
    for (int cg = 0; cg < 4; cg++){
      f32x4 sf[4];
      __builtin_amdgcn_s_setprio(1);
#pragma unroll
      for (int c = 0; c < 4; c++){
        f32x4 z = (f32x4){0.f, 0.f, 0.f, 0.f};
        z = mfma16(kf[c][0], aq[cg][0], z);
        sf[c] = mfma16(kf[c][1], aq[cg][1], z);
      }
      __builtin_amdgcn_s_setprio(0);

      // exp + pack: pw[c] = rows g*4+{0,1} (.x) and {2,3} (.y) of block c
      uint2 pw[4];
#pragma unroll
      for (int c = 0; c < 4; c++){
        float p0 = exp2_fast(__builtin_fmaf(sf[c][0], L2E, -C2));
        float p1 = exp2_fast(__builtin_fmaf(sf[c][1], L2E, -C2));
        float p2 = exp2_fast(__builtin_fmaf(sf[c][2], L2E, -C2));
        float p3 = exp2_fast(__builtin_fmaf(sf[c][3], L2E, -C2));
        pw[c].x = cvt_pk_bf16(p0, p1);
        pw[c].y = cvt_pk_bf16(p2, p3);
      }

      // build K=32 B-fragments via permlane swaps (2 spans: c{0,1}, c{2,3})
      bf16x8 pf[2];
#pragma unroll
      for (int sp = 0; sp < 2; sp++){
        u32x2 tx = __builtin_amdgcn_permlane32_swap(pw[sp*2].x, pw[sp*2+1].x, false, false);
        u32x2 fx = __builtin_amdgcn_permlane16_swap(tx.x, tx.y, false, false);
        u32x2 ty = __builtin_amdgcn_permlane32_swap(pw[sp*2].y, pw[sp*2+1].y, false, false);
        u32x2 fy = __builtin_amdgcn_permlane16_swap(ty.x, ty.y, false, false);
        union { u32 w[4]; bf16x8 v; } pu;
        pu.w[0] = fx.x;   // rows g*8+0,1
        pu.w[1] = fy.x;   // rows g*8+2,3
        pu.w[2] = fx.y;   // rows g*8+4,5
        pu.w[3] = fy.y;   // rows g*8+6,7
        pf[sp] = pu.v;
      }

      __builtin_amdgcn_s_setprio(1);
#pragma unroll
      for (int cd = 0; cd < 4; cd++){
        acc[cg][cd] = mfma16(vf[cd][0], pf[0], acc[cg][cd]);
        acc[cg][cd] = mfma16(vf[cd][1], pf[1], acc[cg][cd]);
      }
      lacc[cg] = mfma16(ones, pf[0], lacc[cg]);
      lacc[cg] = mfma16(ones, pf[1], lacc[cg]);
      __builtin_amdgcn_s_setprio(0);
    }

    __syncthreads();
    buf ^= 1;
  }

  // ---- combine the two k-halves (scratch aliases dead K/V LDS) -------------
  f32x4* sAcc = (f32x4*)lds;                     // 16*256 f32x4 = 64KB
  float*  sL  = (float*)((char*)lds + 65536);    // 4*256 f32 = 4KB
  if (kg == 1){
#pragma unroll
    for (int cg = 0; cg < 4; cg++){
#pragma unroll
      for (int cd = 0; cd < 4; cd++)
        sAcc[(cg * 4 + cd) * 256 + wq * 64 + lane] = acc[cg][cd];
      sL[cg * 256 + wq * 64 + lane] = lacc[cg][0];
    }
  }
  __syncthreads();
  if (kg == 0){
#pragma unroll
    for (int cg = 0; cg < 4; cg++){
      float l = lacc[cg][0] + sL[cg * 256 + wq * 64 + lane];
      float linv = 1.f / l;
      int s = q0 + cg * 16 + col;
#pragma unroll
      for (int cd = 0; cd < 4; cd++){
        f32x4 a = acc[cg][cd] + sAcc[(cg * 4 + cd) * 256 + wq * 64 + lane];
        uint2 o;
        o.x = cvt_pk_bf16(a[0] * linv, a[1] * linv);
        o.y = cvt_pk_bf16(a[2] * linv, a[3] * linv);
        int pc = (cd * 2 + (g >> 1)) ^ sw;   // pre-swizzle for Wo GEMM
        *(uint2*)(AO + (size_t)(b * S + s) * 1024 + h * 64 + pc * 8 + (g & 1) * 4) = o;
      }
    }
  }
}

// ---------------- host-side launch ------------------------------------------
extern "C" void kernel_launch(void* const* d_in, const int* in_sizes, int n_in,
                              void* d_out, int out_size, void* d_ws, size_t ws_size,
                              hipStream_t stream){
  const int Btok = 8192;          // B*S
  const float* hs   = (const float*)d_in[0];
  const float* cosb = (const float*)d_in[1];
  const float* sinb = (const float*)d_in[2];
  const float* Wq = (const float*)d_in[5];
  const float* Wk = (const float*)d_in[6];
  const float* Wv = (const float*)d_in[7];
  const float* Wo = (const float*)d_in[8];
  const float* qw = (const float*)d_in[9];
  const float* kw = (const float*)d_in[10];
  float* out = (float*)d_out;

  char* ws = (char*)d_ws;
  u16* hsB   = (u16*)ws;               ws += (size_t)Btok * 1024 * 2;   // 16MB
  u16* WqkvT = (u16*)ws;               ws += (size_t)2048 * 1024 * 2;   // 4MB
  u16* WoT   = (u16*)ws;               ws += (size_t)1024 * 1024 * 2;   // 2MB
  u16* Qn    = (u16*)ws;               ws += (size_t)Btok * 1024 * 2;   // 16MB
  u16* Kn    = (u16*)ws;               ws += (size_t)Btok * 512  * 2;   // 8MB
  u16* Vn    = (u16*)ws;               ws += (size_t)Btok * 512  * 2;   // 8MB
  float2* cst = (float2*)ws;           ws += (size_t)2048 * 64 * 8;     // 1MB
  u16* AO    = hsB;                    // alias: hsB dead after QKV GEMM

  f32_to_bf16_swz<<<2048, 256, 0, stream>>>(hs, hsB, Btok * 128);

  dim3 tb(32, 32);
  conv_transpose_swz<<<dim3(32, 32), tb, 0, stream>>>(Wq, WqkvT,               1024, 1024);
  conv_transpose_swz<<<dim3(16, 32), tb, 0, stream>>>(Wk, WqkvT + 1024 * 1024, 1024, 512);
  conv_transpose_swz<<<dim3(16, 32), tb, 0, stream>>>(Wv, WqkvT + 1536 * 1024, 1024, 512);
  conv_transpose_swz<<<dim3(32, 32), tb, 0, stream>>>(Wo, WoT,                 1024, 1024);
  pack_cs<<<512, 256, 0, stream>>>(cosb, sinb, cst, 2048 * 64);

  gemm256<256, 128, 1><<<dim3(8, 32), 512, 0, stream>>>(
      hsB, WqkvT, nullptr, Btok, 2048, 1024, cst, qw, kw, Qn, Kn, Vn);

  flash_attn<<<512, 512, 0, stream>>>(Qn, Kn, Vn, AO);

  gemm256<128, 64, 2><<<dim3(4, 64), 512, 0, stream>>>(
      AO, WoT, out, Btok, 1024, 1024, nullptr, nullptr, nullptr,
      nullptr, nullptr, nullptr);
}

// Round 19
// 173.341 us; speedup vs baseline: 1.1958x; 1.0626x over previous
//
#include <hip/hip_runtime.h>
#include <stdint.h>
#include <stddef.h>

typedef unsigned short u16;
typedef unsigned int   u32;
typedef unsigned short u16x8 __attribute__((ext_vector_type(8)));
typedef unsigned int   u32x2 __attribute__((ext_vector_type(2)));
typedef __attribute__((ext_vector_type(8))) __bf16 bf16x8;
typedef __attribute__((ext_vector_type(4))) float f32x4;

__device__ __forceinline__ float bf2f(u16 v){
  union { unsigned u; float f; } x; x.u = ((unsigned)v) << 16; return x.f;
}
__device__ __forceinline__ u16 f2bf(float f){
  union { float f; unsigned u; } x; x.f = f;
  return (u16)((x.u + 0x7fffu + ((x.u >> 16) & 1u)) >> 16);
}

__device__ __forceinline__ float exp2_fast(float x){
  float r; asm("v_exp_f32 %0, %1" : "=v"(r) : "v"(x)); return r;
}
__device__ __forceinline__ u32 cvt_pk_bf16(float lo, float hi){
  u32 r; asm("v_cvt_pk_bf16_f32 %0, %1, %2" : "=v"(r) : "v"(lo), "v"(hi)); return r;
}

__device__ __forceinline__ f32x4 mfma16(bf16x8 a, bf16x8 b, f32x4 c){
  return __builtin_amdgcn_mfma_f32_16x16x32_bf16(a, b, c, 0, 0, 0);
}

#define AS1 __attribute__((address_space(1)))
#define AS3 __attribute__((address_space(3)))
__device__ __forceinline__ void gload_lds16(const void* g, void* l){
  __builtin_amdgcn_global_load_lds((const AS1 void*)g, (AS3 void*)l, 16, 0, 0);
}

// ---------------- fused prep: 4 weight transposes + hs f32->bf16 + cos/sin --
// blocks [0,3072): transpose+convert+swizzle (out rows length 1024)
// blocks [3072,3584): hs fp32 -> bf16 pre-swizzled chunks
// blocks [3584,3712): pack cos/sin float2
__global__ void prep_all(const float* __restrict__ hs, u16* __restrict__ hsB,
                         const float* __restrict__ Wq, const float* __restrict__ Wk,
                         const float* __restrict__ Wv, const float* __restrict__ Wo,
                         u16* __restrict__ WqkvT, u16* __restrict__ WoT,
                         const float* __restrict__ cosb, const float* __restrict__ sinb,
                         float2* __restrict__ cs){
  __shared__ float tbuf[32][33];
  const int blk = blockIdx.x;
  const int t = threadIdx.x;
  if (blk < 3072){
    const float* in; u16* out; int C, bx, by;
    if (blk < 1024){ in = Wq; out = WqkvT; C = 1024; bx = blk & 31; by = blk >> 5; }
    else if (blk < 1536){ int q = blk - 1024; in = Wk; out = WqkvT + 1024 * 1024; C = 512; bx = q & 15; by = q >> 4; }
    else if (blk < 2048){ int q = blk - 1536; in = Wv; out = WqkvT + 1536 * 1024; C = 512; bx = q & 15; by = q >> 4; }
    else { int q = blk - 2048; in = Wo; out = WoT; C = 1024; bx = q & 31; by = q >> 5; }
    int tx = t & 31, ty = t >> 5;
    int c0 = bx * 32, r0 = by * 32;
    tbuf[ty][tx] = in[(size_t)(r0 + ty) * C + c0 + tx];
    __syncthreads();
    if (t < 128){
      int orow = t >> 2, oc = t & 3;
      int gr = c0 + orow;
      int gc = (r0 >> 3) + oc;
      int gcs = (gc & ~7) | ((gc & 7) ^ (gr & 7));
      u16x8 v;
#pragma unroll
      for (int i = 0; i < 8; i++) v[i] = f2bf(tbuf[oc * 8 + i][orow]);
      *(u16x8*)(out + (size_t)gr * 1024 + gcs * 8) = v;
    }
  } else if (blk < 3584){
    for (int i = (blk - 3072) * 1024 + t; i < 1048576; i += 524288){
      int row = i >> 7, c = i & 127;
      int cst = (c & ~7) | ((c & 7) ^ (row & 7));
      const float* p = hs + ((size_t)i << 3);
      float4 v0 = *(const float4*)p;
      float4 v1 = *(const float4*)(p + 4);
      u16x8 o = { f2bf(v0.x), f2bf(v0.y), f2bf(v0.z), f2bf(v0.w),
                  f2bf(v1.x), f2bf(v1.y), f2bf(v1.z), f2bf(v1.w) };
      *(u16x8*)(hsB + (((size_t)row << 7) + cst) * 8) = o;
    }
  } else {
    int i = (blk - 3584) * 1024 + t;           // 128*1024 = 131072 exact
    cs[i] = (float2){cosb[i], sinb[i]};
  }
}

// ---------------- GEMM: BM x 256 tile, BK=64, 8 waves, BOTH operands staged -
// A (M x K) and Bt (N x K) pre-swizzled; 2-buffer, STAGE(t+1) issued before
// compute(t) so the end-of-tile vmcnt(0) is fully covered by compute.
// EPI: 1 = fused QKV epilogue (RMSNorm+RoPE+relayout), 2 = f32 C.
template<int BM, int WM, int EPI>
__global__ __launch_bounds__(512, 2)
void gemmB(const u16* __restrict__ A, const u16* __restrict__ Bt,
           void* __restrict__ Cv, int M, int N, int K,
           const float2* __restrict__ cs, const float* __restrict__ qw,
           const float* __restrict__ kw, u16* __restrict__ Qn,
           u16* __restrict__ Kn, u16* __restrict__ Vn){
  constexpr int MF = WM / 16;
  constexpr int ALOADS = BM / 64;
  __shared__ __align__(16) u16 Ab[2][BM * 64];
  __shared__ __align__(16) u16 Bb[2][256 * 64];
  const int tid = threadIdx.x;
  const int wid = tid >> 6, lane = tid & 63;
  const int g = lane >> 4, col = lane & 15;
  const int wm = wid >> 2, wn = wid & 3;
  const int swz = col & 7;

  int nb  = gridDim.x * gridDim.y;
  int lid = blockIdx.y * gridDim.x + blockIdx.x;
  int cpx = nb >> 3;
  int sid = (lid & 7) * cpx + (lid >> 3);
  int bx  = sid % gridDim.x, by = sid / gridDim.x;
  const int m0 = by * BM, n0 = bx * 256;

  f32x4 acc[MF][4];
#pragma unroll
  for (int i = 0; i < MF; i++)
#pragma unroll
    for (int j = 0; j < 4; j++) acc[i][j] = (f32x4){0.f, 0.f, 0.f, 0.f};

  const int arow = wid * 8 + (lane >> 3);
  const int acl  = (lane & 7) * 8;

  auto STAGE = [&](int bi, int k0){
#pragma unroll
    for (int j = 0; j < ALOADS; j++)
      gload_lds16(A + (size_t)(m0 + j * 64 + arow) * K + k0 + acl,
                  &Ab[bi][j * 4096 + wid * 512]);
#pragma unroll
    for (int j = 0; j < 4; j++)
      gload_lds16(Bt + (size_t)(n0 + j * 64 + arow) * K + k0 + acl,
                  &Bb[bi][j * 4096 + wid * 512]);
  };

  const int NT = K >> 6;
  STAGE(0, 0);
  asm volatile("s_waitcnt vmcnt(0)");
  __builtin_amdgcn_sched_barrier(0);
  __builtin_amdgcn_s_barrier();
  __builtin_amdgcn_sched_barrier(0);

  int buf = 0;
  for (int t = 0; t < NT; ++t){
    if (t + 1 < NT) STAGE(buf ^ 1, (t + 1) * 64);
    __builtin_amdgcn_sched_barrier(0);

    const u16* Ac = &Ab[buf][0];
    const u16* Bc = &Bb[buf][0];
    bf16x8 bfr[4][2];
#pragma unroll
    for (int ni = 0; ni < 4; ni++){
      int row = wn * 64 + ni * 16 + col;
#pragma unroll
      for (int ks = 0; ks < 2; ks++)
        bfr[ni][ks] = *(const bf16x8*)&Bc[row * 64 + (((ks * 4 + g) ^ swz) << 3)];
    }
#pragma unroll
    for (int ph = 0; ph < MF / 4; ++ph){
      bf16x8 afr[4][2];
#pragma unroll
      for (int m2 = 0; m2 < 4; m2++){
        int row = wm * WM + (ph * 4 + m2) * 16 + col;
#pragma unroll
        for (int ks = 0; ks < 2; ks++)
          afr[m2][ks] = *(const bf16x8*)&Ac[row * 64 + (((ks * 4 + g) ^ swz) << 3)];
      }
      __builtin_amdgcn_s_setprio(1);
#pragma unroll
      for (int m2 = 0; m2 < 4; m2++)
#pragma unroll
        for (int ni = 0; ni < 4; ni++)
#pragma unroll
          for (int ks = 0; ks < 2; ks++)
            acc[ph * 4 + m2][ni] =
                mfma16(afr[m2][ks], bfr[ni][ks], acc[ph * 4 + m2][ni]);
      __builtin_amdgcn_s_setprio(0);
    }

    asm volatile("s_waitcnt lgkmcnt(0)");
    __builtin_amdgcn_sched_barrier(0);
    asm volatile("s_waitcnt vmcnt(0)");
    __builtin_amdgcn_sched_barrier(0);
    __builtin_amdgcn_s_barrier();
    __builtin_amdgcn_sched_barrier(0);
    buf ^= 1;
  }

  if (EPI == 1){
    // ---- fused RMSNorm + RoPE + relayout epilogue ----
    const int colbase = n0 + wn * 64;    // wave owns one 64-wide head
    const int t0 = m0 + wm * WM;
    const int bb = t0 >> 11;
    if (colbase < 1536){
      const bool isQ = colbase < 1024;
      const int head = isQ ? (colbase >> 6) : ((colbase - 1024) >> 6);
      const float* wp = isQ ? qw : kw;
      float wv[4];
#pragma unroll
      for (int ni = 0; ni < 4; ni++) wv[ni] = wp[ni * 16 + col];
      u16* outp = isQ ? Qn : Kn;
      size_t hb = isQ ? ((size_t)(bb * 16 + head) * 2048)
                      : ((size_t)(bb * 8 + head) * 2048);
#pragma unroll
      for (int mi = 0; mi < MF; mi++){
        f32x4 ssv = (f32x4){0.f, 0.f, 0.f, 0.f};
#pragma unroll
        for (int ni = 0; ni < 4; ni++)
#pragma unroll
          for (int r = 0; r < 4; r++) ssv[r] += acc[mi][ni][r] * acc[mi][ni][r];
#pragma unroll
        for (int off = 1; off < 16; off <<= 1)
#pragma unroll
          for (int r = 0; r < 4; r++) ssv[r] += __shfl_xor(ssv[r], off, 64);
        f32x4 rinv;
#pragma unroll
        for (int r = 0; r < 4; r++) rinv[r] = rsqrtf(ssv[r] * (1.f / 64.f) + 1e-6f);
        int s0 = (t0 + mi * 16 + g * 4) & 2047;
#pragma unroll
        for (int np = 0; np < 2; np++){
          int d0 = np * 32 + col, d1 = d0 + 16;
#pragma unroll
          for (int r = 0; r < 4; r++){
            int s = s0 + r;
            float y0 = acc[mi][np * 2][r]     * rinv[r] * wv[np * 2];
            float y1 = acc[mi][np * 2 + 1][r] * rinv[r] * wv[np * 2 + 1];
            float2 c0 = cs[s * 64 + d0];
            float2 c1 = cs[s * 64 + d1];
            float o0 = y0 * c0.x - y1 * c0.y;
            float o1 = y1 * c1.x + y0 * c1.y;
            if (isQ){
              outp[(hb + s) * 64 + d0] = f2bf(o0);
              outp[(hb + s) * 64 + d1] = f2bf(o1);
            } else {
              int z0 = ((((d0 >> 3) ^ s) & 7) << 3) | (d0 & 7);
              int z1 = ((((d1 >> 3) ^ s) & 7) << 3) | (d1 & 7);
              outp[(hb + s) * 64 + z0] = f2bf(o0);
              outp[(hb + s) * 64 + z1] = f2bf(o1);
            }
          }
        }
      }
    } else {
      const int kvh = (colbase - 1536) >> 6;
      const size_t vb0 = (size_t)(bb * 8 + kvh) * 64;
#pragma unroll
      for (int mi = 0; mi < MF; mi++){
        f32x4 ssv = (f32x4){0.f, 0.f, 0.f, 0.f};
#pragma unroll
        for (int ni = 0; ni < 4; ni++)
#pragma unroll
          for (int r = 0; r < 4; r++) ssv[r] += acc[mi][ni][r] * acc[mi][ni][r];
#pragma unroll
        for (int off = 1; off < 16; off <<= 1)
#pragma unroll
          for (int r = 0; r < 4; r++) ssv[r] += __shfl_xor(ssv[r], off, 64);
        f32x4 rinv;
#pragma unroll
        for (int r = 0; r < 4; r++) rinv[r] = rsqrtf(ssv[r] * (1.f / 64.f) + 1e-6f);
        int s0 = (t0 + mi * 16 + g * 4) & 2047;
#pragma unroll
        for (int ni = 0; ni < 4; ni++){
          int d = ni * 16 + col;
          uint2 o;
          o.x = cvt_pk_bf16(acc[mi][ni][0] * rinv[0], acc[mi][ni][1] * rinv[1]);
          o.y = cvt_pk_bf16(acc[mi][ni][2] * rinv[2], acc[mi][ni][3] * rinv[3]);
          size_t addr = (vb0 + d) * 2048 + (s0 & ~63)
                      + ((((s0 >> 3) ^ (d & 7)) & 7) << 3) + (s0 & 7);
          *(uint2*)(Vn + addr) = o;
        }
      }
    }
    return;
  }

#pragma unroll
  for (int mi = 0; mi < MF; mi++)
#pragma unroll
    for (int ni = 0; ni < 4; ni++)
#pragma unroll
      for (int r = 0; r < 4; r++){
        int row = m0 + wm * WM + mi * 16 + g * 4 + r;
        int cc  = n0 + wn * 64 + ni * 16 + col;
        ((float*)Cv)[(size_t)row * N + cc] = acc[mi][ni][r];
      }
}

// ---------------- Flash attention: 8 waves (4 q x 2 kg), in-register P ------
// r18 configuration (unchanged): XCD-grouped 1D grid, in-register P via
// permlane swaps, ones-MFMA l, 2-buffer K/V staging.
__global__ __launch_bounds__(512, 2)
void flash_attn(const u16* __restrict__ Qn, const u16* __restrict__ Kn,
                const u16* __restrict__ Vn, u16* __restrict__ AO){
  const int S = 2048;
  const float L2E = 1.4426950408889634f;
  const float C2 = 30.f;
  const int i = blockIdx.x;
  const int hb = (i & 7) | ((i >> 6) << 3);
  const int qt = (i >> 3) & 7;
  const int h = hb & 15, b = hb >> 4;
  const int kvh = h >> 1;
  const int wid = threadIdx.x >> 6, lane = threadIdx.x & 63;
  const int kg = wid >> 2, wq = wid & 3;
  const int g = lane >> 4, col = lane & 15;
  const int q0 = qt * 256 + wq * 64;

  __shared__ __align__(16) u16 lds[34816];
  u16* Kl = lds + kg * 8192;
  u16* Vl = lds + 16384 + kg * 8192;

  bf16x8 ones;
#pragma unroll
  for (int k = 0; k < 8; k++) ones[k] = (__bf16)1.0f;

  bf16x8 aq[4][2];
#pragma unroll
  for (int cg = 0; cg < 4; cg++){
    const u16* qp = Qn + ((size_t)((b * 16 + h) * S) + q0 + cg * 16 + col) * 64;
    aq[cg][0] = *(const bf16x8*)(qp + g * 8);
    aq[cg][1] = *(const bf16x8*)(qp + 32 + g * 8);
  }

  const u16* Kbase = Kn + (size_t)(b * 8 + kvh) * S * 64 + (size_t)kg * 1024 * 64;
  const u16* Vbase = Vn + (size_t)(b * 8 + kvh) * 64 * S;
  const int vcol0 = kg * 1024;

  f32x4 acc[4][4];
  f32x4 lacc[4];
#pragma unroll
  for (int cg = 0; cg < 4; cg++){
    lacc[cg] = (f32x4){0.f, 0.f, 0.f, 0.f};
#pragma unroll
    for (int k = 0; k < 4; k++) acc[cg][k] = (f32x4){0.f, 0.f, 0.f, 0.f};
  }

  const int sw = col & 7;

  auto STAGE = [&](int bi, int ktl){
    int kc0 = ktl * 64;
#pragma unroll
    for (int cc = 0; cc < 2; cc++){
      int chunk = cc * 4 + wq;
      gload_lds16(Kbase + (size_t)kc0 * 64 + chunk * 512 + lane * 8,
                  Kl + bi * 4096 + chunk * 512);
      int drow = chunk * 8 + (lane >> 3);
      gload_lds16(Vbase + (size_t)drow * S + vcol0 + kc0 + (lane & 7) * 8,
                  Vl + bi * 4096 + chunk * 512);
    }
  };

  int buf = 0;
  STAGE(0, 0);
  __syncthreads();

  for (int kt = 0; kt < 16; ++kt){
    if (kt + 1 < 16) STAGE(buf ^ 1, kt + 1);

    const u16* Kb = Kl + buf * 4096;
    const u16* Vb = Vl + buf * 4096;

    bf16x8 kf[4][2], vf[4][2];
#pragma unroll
    for (int c = 0; c < 4; c++){
      const u16* kb = Kb + (c * 16 + col) * 64;
      kf[c][0] = *(const bf16x8*)(kb + (g ^ sw) * 8);
      kf[c][1] = *(const bf16x8*)(kb + ((4 + g) ^ sw) * 8);
      const u16* vb = Vb + (c * 16 + col) * 64;
      vf[c][0] = *(const bf16x8*)(vb + (g ^ sw) * 8);
      vf[c][1] = *(const bf16x8*)(vb + ((4 + g) ^ sw) * 8);
    }

#pragma unroll
    for (int cg = 0; cg < 4; cg++){
      f32x4 sf[4];
      __builtin_amdgcn_s_setprio(1);
#pragma unroll
      for (int c = 0; c < 4; c++){
        f32x4 z = (f32x4){0.f, 0.f, 0.f, 0.f};
        z = mfma16(kf[c][0], aq[cg][0], z);
        sf[c] = mfma16(kf[c][1], aq[cg][1], z);
      }
      __builtin_amdgcn_s_setprio(0);

      uint2 pw[4];
#pragma unroll
      for (int c = 0; c < 4; c++){
        float p0 = exp2_fast(__builtin_fmaf(sf[c][0], L2E, -C2));
        float p1 = exp2_fast(__builtin_fmaf(sf[c][1], L2E, -C2));
        float p2 = exp2_fast(__builtin_fmaf(sf[c][2], L2E, -C2));
        float p3 = exp2_fast(__builtin_fmaf(sf[c][3], L2E, -C2));
        pw[c].x = cvt_pk_bf16(p0, p1);
        pw[c].y = cvt_pk_bf16(p2, p3);
      }

      bf16x8 pf[2];
#pragma unroll
      for (int sp = 0; sp < 2; sp++){
        u32x2 tx = __builtin_amdgcn_permlane32_swap(pw[sp*2].x, pw[sp*2+1].x, false, false);
        u32x2 fx = __builtin_amdgcn_permlane16_swap(tx.x, tx.y, false, false);
        u32x2 ty = __builtin_amdgcn_permlane32_swap(pw[sp*2].y, pw[sp*2+1].y, false, false);
        u32x2 fy = __builtin_amdgcn_permlane16_swap(ty.x, ty.y, false, false);
        union { u32 w[4]; bf16x8 v; } pu;
        pu.w[0] = fx.x;
        pu.w[1] = fy.x;
        pu.w[2] = fx.y;
        pu.w[3] = fy.y;
        pf[sp] = pu.v;
      }

      __builtin_amdgcn_s_setprio(1);
#pragma unroll
      for (int cd = 0; cd < 4; cd++){
        acc[cg][cd] = mfma16(vf[cd][0], pf[0], acc[cg][cd]);
        acc[cg][cd] = mfma16(vf[cd][1], pf[1], acc[cg][cd]);
      }
      lacc[cg] = mfma16(ones, pf[0], lacc[cg]);
      lacc[cg] = mfma16(ones, pf[1], lacc[cg]);
      __builtin_amdgcn_s_setprio(0);
    }

    __syncthreads();
    buf ^= 1;
  }

  f32x4* sAcc = (f32x4*)lds;
  float*  sL  = (float*)((char*)lds + 65536);
  if (kg == 1){
#pragma unroll
    for (int cg = 0; cg < 4; cg++){
#pragma unroll
      for (int cd = 0; cd < 4; cd++)
        sAcc[(cg * 4 + cd) * 256 + wq * 64 + lane] = acc[cg][cd];
      sL[cg * 256 + wq * 64 + lane] = lacc[cg][0];
    }
  }
  __syncthreads();
  if (kg == 0){
#pragma unroll
    for (int cg = 0; cg < 4; cg++){
      float l = lacc[cg][0] + sL[cg * 256 + wq * 64 + lane];
      float linv = 1.f / l;
      int s = q0 + cg * 16 + col;
#pragma unroll
      for (int cd = 0; cd < 4; cd++){
        f32x4 a = acc[cg][cd] + sAcc[(cg * 4 + cd) * 256 + wq * 64 + lane];
        uint2 o;
        o.x = cvt_pk_bf16(a[0] * linv, a[1] * linv);
        o.y = cvt_pk_bf16(a[2] * linv, a[3] * linv);
        int pc = (cd * 2 + (g >> 1)) ^ sw;
        *(uint2*)(AO + (size_t)(b * S + s) * 1024 + h * 64 + pc * 8 + (g & 1) * 4) = o;
      }
    }
  }
}

// ---------------- host-side launch ------------------------------------------
extern "C" void kernel_launch(void* const* d_in, const int* in_sizes, int n_in,
                              void* d_out, int out_size, void* d_ws, size_t ws_size,
                              hipStream_t stream){
  const int Btok = 8192;          // B*S
  const float* hs   = (const float*)d_in[0];
  const float* cosb = (const float*)d_in[1];
  const float* sinb = (const float*)d_in[2];
  const float* Wq = (const float*)d_in[5];
  const float* Wk = (const float*)d_in[6];
  const float* Wv = (const float*)d_in[7];
  const float* Wo = (const float*)d_in[8];
  const float* qw = (const float*)d_in[9];
  const float* kw = (const float*)d_in[10];
  float* out = (float*)d_out;

  char* ws = (char*)d_ws;
  u16* hsB   = (u16*)ws;               ws += (size_t)Btok * 1024 * 2;   // 16MB
  u16* WqkvT = (u16*)ws;               ws += (size_t)2048 * 1024 * 2;   // 4MB
  u16* WoT   = (u16*)ws;               ws += (size_t)1024 * 1024 * 2;   // 2MB
  u16* Qn    = (u16*)ws;               ws += (size_t)Btok * 1024 * 2;   // 16MB
  u16* Kn    = (u16*)ws;               ws += (size_t)Btok * 512  * 2;   // 8MB
  u16* Vn    = (u16*)ws;               ws += (size_t)Btok * 512  * 2;   // 8MB
  float2* cst = (float2*)ws;           ws += (size_t)2048 * 64 * 8;     // 1MB
  u16* AO    = hsB;                    // alias: hsB dead after QKV GEMM

  prep_all<<<3712, 1024, 0, stream>>>(hs, hsB, Wq, Wk, Wv, Wo, WqkvT, WoT,
                                      cosb, sinb, cst);

  gemmB<256, 128, 1><<<dim3(8, 32), 512, 0, stream>>>(
      hsB, WqkvT, nullptr, Btok, 2048, 1024, cst, qw, kw, Qn, Kn, Vn);

  flash_attn<<<512, 512, 0, stream>>>(Qn, Kn, Vn, AO);

  gemmB<128, 64, 2><<<dim3(4, 64), 512, 0, stream>>>(
      AO, WoT, out, Btok, 1024, 1024, nullptr, nullptr, nullptr,
      nullptr, nullptr, nullptr);
}